// Round 11
// baseline (253.853 us; speedup 1.0000x reference)
//
#include <hip/hip_runtime.h>
#include <hip/hip_bf16.h>
#include <cstdint>

// Problem constants
#define BB   16
#define PP   1024
#define EE   768
#define HID  768
#define NH   12
#define DH   64
#define NPB  (PP * EE)          // 786432 elements per batch
#define MROWS (BB * PP)         // 16384

typedef __bf16 bf16_t;
typedef __bf16 bf16x8 __attribute__((ext_vector_type(8)));
typedef float  f32x4  __attribute__((ext_vector_type(4)));

// Async global->LDS 16B DMA. LDS dest must be wave-uniform base + lane*16.
__device__ __forceinline__ void gld16(const void* g, void* l) {
    __builtin_amdgcn_global_load_lds(
        (const __attribute__((address_space(1))) void*)(uintptr_t)g,
        (__attribute__((address_space(3))) void*)(uint32_t)(uintptr_t)l,
        16, 0, 0);
}

// ---------------------------------------------------------------------------
// stats+prep fused: blocks [0,1024): per-slice partial sums of x.
// [1024,1456): qkvT transpose tiles; [1456,1600): lwT tiles.
// ---------------------------------------------------------------------------
__global__ __launch_bounds__(256) void stats_prep_kernel(const float* __restrict__ x,
                                                         const float* __restrict__ qkvw,
                                                         const float* __restrict__ linw,
                                                         float* __restrict__ part,
                                                         bf16_t* __restrict__ qkvT,
                                                         bf16_t* __restrict__ lwT) {
    int bid = blockIdx.x;
    if (bid < 1024) {
        int b = bid >> 6, s = bid & 63;
        const float4* xp = (const float4*)(x + (size_t)b * NPB + (size_t)s * 12288);
        float sum = 0.f, ss = 0.f;
#pragma unroll
        for (int i = 0; i < 12; ++i) {
            float4 v = xp[i * 256 + threadIdx.x];
            sum += v.x + v.y + v.z + v.w;
            ss  += v.x * v.x + v.y * v.y + v.z * v.z + v.w * v.w;
        }
#pragma unroll
        for (int off = 32; off > 0; off >>= 1) {
            sum += __shfl_down(sum, off, 64);
            ss  += __shfl_down(ss,  off, 64);
        }
        __shared__ float tmp[8];
        int wave = threadIdx.x >> 6, lane = threadIdx.x & 63;
        if (lane == 0) { tmp[wave * 2] = sum; tmp[wave * 2 + 1] = ss; }
        __syncthreads();
        if (threadIdx.x == 0) {
            part[bid * 2]     = tmp[0] + tmp[2] + tmp[4] + tmp[6];
            part[bid * 2 + 1] = tmp[1] + tmp[3] + tmp[5] + tmp[7];
        }
    } else {
        __shared__ float lds[64][65];
        int pid = bid - 1024;
        const float* src; bf16_t* dst; int r0, c0, W;
        if (pid < 432) {
            int tr = pid / 36, tc = pid - tr * 36;
            r0 = tr * 64; c0 = tc * 64; src = qkvw; W = 2304; dst = qkvT;
        } else {
            int bb = pid - 432;
            int tr = bb / 12, tc = bb - tr * 12;
            r0 = tr * 64; c0 = tc * 64; src = linw; W = 768; dst = lwT;
        }
        int t = threadIdx.x;
        int rr = t >> 4, cc4 = (t & 15) * 4;
#pragma unroll
        for (int j = 0; j < 4; ++j) {
            float4 v = *(const float4*)(src + (size_t)(r0 + rr + j * 16) * W + c0 + cc4);
            lds[rr + j * 16][cc4 + 0] = v.x;
            lds[rr + j * 16][cc4 + 1] = v.y;
            lds[rr + j * 16][cc4 + 2] = v.z;
            lds[rr + j * 16][cc4 + 3] = v.w;
        }
        __syncthreads();
        int cl = t >> 3, rgl = (t & 7) * 8;
#pragma unroll
        for (int jj = 0; jj < 2; ++jj) {
            int c = jj * 32 + cl;
            union { bf16_t h[8]; uint4 u; } o;
#pragma unroll
            for (int k = 0; k < 8; ++k) o.h[k] = (bf16_t)lds[rgl + k][c];
            *(uint4*)(dst + (size_t)(c0 + c) * 768 + r0 + rgl) = o.u;
        }
    }
}

// ---------------------------------------------------------------------------
// ln_apply: fp32 x read + inline stats finalize (64 partial pairs per batch,
// L2-hot). b uniform per block.
// ---------------------------------------------------------------------------
__global__ __launch_bounds__(256) void ln_apply_kernel(const float* __restrict__ x,
                                                       const float* __restrict__ lnw,
                                                       const float* __restrict__ lnb,
                                                       const float* __restrict__ part,
                                                       bf16_t* __restrict__ xn) {
    int i = (blockIdx.x * 256 + threadIdx.x) * 8;
    int b = i / NPB;
    int r = i - b * NPB;
    int lane = threadIdx.x & 63;
    float sum = part[(b * 64 + lane) * 2];
    float ss  = part[(b * 64 + lane) * 2 + 1];
#pragma unroll
    for (int off = 32; off > 0; off >>= 1) {
        sum += __shfl_down(sum, off, 64);
        ss  += __shfl_down(ss,  off, 64);
    }
    const float inv_n = 1.f / (float)NPB;
    float mean = __shfl(sum, 0, 64) * inv_n;
    float var  = __shfl(ss,  0, 64) * inv_n - mean * mean;
    float rstd = rsqrtf(var + 1e-5f);

    float4 x0 = *(const float4*)(x + i),     x1 = *(const float4*)(x + i + 4);
    float4 w0 = *(const float4*)(lnw + r),   w1 = *(const float4*)(lnw + r + 4);
    float4 c0 = *(const float4*)(lnb + r),   c1 = *(const float4*)(lnb + r + 4);
    union { bf16_t h[8]; uint4 u; } o;
    o.h[0] = (bf16_t)((x0.x - mean) * rstd * w0.x + c0.x);
    o.h[1] = (bf16_t)((x0.y - mean) * rstd * w0.y + c0.y);
    o.h[2] = (bf16_t)((x0.z - mean) * rstd * w0.z + c0.z);
    o.h[3] = (bf16_t)((x0.w - mean) * rstd * w0.w + c0.w);
    o.h[4] = (bf16_t)((x1.x - mean) * rstd * w1.x + c1.x);
    o.h[5] = (bf16_t)((x1.y - mean) * rstd * w1.y + c1.y);
    o.h[6] = (bf16_t)((x1.z - mean) * rstd * w1.z + c1.z);
    o.h[7] = (bf16_t)((x1.w - mean) * rstd * w1.w + c1.w);
    *(uint4*)(xn + i) = o.u;
}

// ---------------------------------------------------------------------------
// Shared core (gemm_out): 128x128 tile, BK=32, TRIPLE-buffered (48KB ->
// 3 blocks/CU), counted vmcnt(8), 4 waves (2Mx2N, wave tile 64x64).
// ---------------------------------------------------------------------------
__device__ __forceinline__ void core128_bk32(const bf16_t* __restrict__ A,
                                             const bf16_t* __restrict__ Bt,
                                             int mBase, int nBase,
                                             f32x4 acc[4][4], bf16_t* smem) {
    const int t = threadIdx.x, lane = t & 63, wave = t >> 6;
    const int wm = wave >> 1, wn = wave & 1;
    const int m16 = lane & 15, quad = lane >> 4;

    const bf16_t* gsrc[4];
    int ldst[4];
#pragma unroll
    for (int j = 0; j < 2; ++j) {
        int c = t + 256 * j;
        int l = c >> 3, lg = ((c & 7) - (l & 7)) & 7;
        int row = l + (lg >> 2) * 64, kc = lg & 3;
        gsrc[j]     = A  + (size_t)(mBase + row) * 768 + kc * 8;
        ldst[j]     = c * 8;
        gsrc[2 + j] = Bt + (size_t)(nBase + row) * 768 + kc * 8;
        ldst[2 + j] = 4096 + c * 8;
    }

    int aOff[4], bOff[4];
#pragma unroll
    for (int f = 0; f < 4; ++f) {
        aOff[f] = (f * 16 + m16) * 64 + (((wm * 4 + quad) + (m16 & 7)) & 7) * 8;
        bOff[f] = 4096 + (f * 16 + m16) * 64 + (((wn * 4 + quad) + (m16 & 7)) & 7) * 8;
    }

    const f32x4 z = {0.f, 0.f, 0.f, 0.f};
#pragma unroll
    for (int mf = 0; mf < 4; ++mf)
#pragma unroll
        for (int nf = 0; nf < 4; ++nf) acc[mf][nf] = z;

#pragma unroll
    for (int j = 0; j < 4; ++j) gld16(gsrc[j], smem + ldst[j]);
#pragma unroll
    for (int j = 0; j < 4; ++j) gld16(gsrc[j] + 32, smem + 8192 + ldst[j]);

#pragma unroll
    for (int step = 0; step < 24; ++step) {
        const int cur = (step % 3) * 8192;
        asm volatile("s_waitcnt lgkmcnt(0)" ::: "memory");
        __builtin_amdgcn_sched_barrier(0);
        __builtin_amdgcn_s_barrier();
        if (step + 2 < 24) {
            const int nb = ((step + 2) % 3) * 8192;
            const int kq = (step + 2) * 32;
#pragma unroll
            for (int j = 0; j < 4; ++j)
                gld16(gsrc[j] + kq, smem + nb + ldst[j]);
        }
        if (step < 22)       asm volatile("s_waitcnt vmcnt(8)" ::: "memory");
        else if (step == 22) asm volatile("s_waitcnt vmcnt(4)" ::: "memory");
        else                 asm volatile("s_waitcnt vmcnt(0)" ::: "memory");
        __builtin_amdgcn_sched_barrier(0);
        __builtin_amdgcn_s_barrier();

        bf16x8 af[4], bfv[4];
#pragma unroll
        for (int f = 0; f < 4; ++f) {
            af[f]  = *(const bf16x8*)(smem + cur + aOff[f]);
            bfv[f] = *(const bf16x8*)(smem + cur + bOff[f]);
        }
        __builtin_amdgcn_s_setprio(1);
#pragma unroll
        for (int mf = 0; mf < 4; ++mf)
#pragma unroll
            for (int nf = 0; nf < 4; ++nf)
                acc[mf][nf] = __builtin_amdgcn_mfma_f32_16x16x32_bf16(
                    af[mf], bfv[nf], acc[mf][nf], 0, 0, 0);
        __builtin_amdgcn_s_setprio(0);
    }
}

// ---------------------------------------------------------------------------
// GEMM1 (frozen): tile 128x256, 4 waves, BK=32, triple-buffered (72KB,
// 2 blk/CU), counted vmcnt(12), no mid-step barrier, odd-block anti-phase
// stagger. grid (9,128), 256 thr.
// ---------------------------------------------------------------------------
__global__ __launch_bounds__(256, 2) void gemm_qkv_kernel(const bf16_t* __restrict__ xn,
                                                          const bf16_t* __restrict__ qkvT,
                                                          bf16_t* __restrict__ q,
                                                          bf16_t* __restrict__ kt,
                                                          bf16_t* __restrict__ vt) {
    __shared__ bf16_t smem[36864];   // 72KB: 3 x (A 8KB | B 16KB)
    const int t = threadIdx.x, lane = t & 63, wave = t >> 6;
    const int wm = wave >> 1, wn = wave & 1;
    const int m16 = lane & 15, quad = lane >> 4;

    const int lb = blockIdx.y * 9 + blockIdx.x;
    if (lb & 1) __builtin_amdgcn_s_sleep(28);   // ~1800 cy anti-phase stagger
    const int id = (lb & 7) * 144 + (lb >> 3);
    const int tx = id % 9, ty = id / 9;
    const int mBase = ty * 128, nBase = tx * 256;

    const bf16_t* gsrc[6];
    int ldst[6];
#pragma unroll
    for (int j = 0; j < 2; ++j) {
        int c = t + 256 * j;
        int l = c >> 3, lg = ((c & 7) - (l & 7)) & 7;
        gsrc[j] = xn + (size_t)(mBase + l + (lg >> 2) * 64) * 768 + (lg & 3) * 8;
        ldst[j] = c * 8;
    }
#pragma unroll
    for (int j = 0; j < 4; ++j) {
        int c = t + 256 * j;
        int l = c >> 3, lg = ((c & 7) - (l & 7)) & 7;
        gsrc[2 + j] = qkvT + (size_t)(nBase + l + (lg >> 2) * 128) * 768 + (lg & 3) * 8;
        ldst[2 + j] = 4096 + c * 8;
    }

    int aOff[4], bOff[8];
#pragma unroll
    for (int mf = 0; mf < 4; ++mf)
        aOff[mf] = (mf * 16 + m16) * 64 + (((wm * 4 + quad) + (m16 & 7)) & 7) * 8;
#pragma unroll
    for (int nf = 0; nf < 8; ++nf)
        bOff[nf] = 4096 + (nf * 16 + m16) * 64 + (((wn * 4 + quad) + (m16 & 7)) & 7) * 8;

    f32x4 acc[4][8];
    const f32x4 z = {0.f, 0.f, 0.f, 0.f};
#pragma unroll
    for (int mf = 0; mf < 4; ++mf)
#pragma unroll
        for (int nf = 0; nf < 8; ++nf) acc[mf][nf] = z;

#pragma unroll
    for (int j = 0; j < 6; ++j) gld16(gsrc[j], smem + ldst[j]);
#pragma unroll
    for (int j = 0; j < 6; ++j) gld16(gsrc[j] + 32, smem + 12288 + ldst[j]);

#pragma unroll
    for (int step = 0; step < 24; ++step) {
        const int cur = (step % 3) * 12288;
        asm volatile("s_waitcnt lgkmcnt(0)" ::: "memory");
        __builtin_amdgcn_sched_barrier(0);
        __builtin_amdgcn_s_barrier();
        if (step + 2 < 24) {
            const int nb = ((step + 2) % 3) * 12288;
            const int kq = (step + 2) * 32;
#pragma unroll
            for (int j = 0; j < 6; ++j)
                gld16(gsrc[j] + kq, smem + nb + ldst[j]);
        }
        if (step < 22)       asm volatile("s_waitcnt vmcnt(12)" ::: "memory");
        else if (step == 22) asm volatile("s_waitcnt vmcnt(6)"  ::: "memory");
        else                 asm volatile("s_waitcnt vmcnt(0)"  ::: "memory");
        __builtin_amdgcn_sched_barrier(0);
        __builtin_amdgcn_s_barrier();    // buf[step] globally ready

        bf16x8 af[4], bf0[4], bf1[4];
#pragma unroll
        for (int mf = 0; mf < 4; ++mf)
            af[mf] = *(const bf16x8*)(smem + cur + aOff[mf]);
#pragma unroll
        for (int nf = 0; nf < 4; ++nf)
            bf0[nf] = *(const bf16x8*)(smem + cur + bOff[nf]);
#pragma unroll
        for (int nf = 0; nf < 4; ++nf)
            bf1[nf] = *(const bf16x8*)(smem + cur + bOff[4 + nf]);
        __builtin_amdgcn_s_setprio(1);
#pragma unroll
        for (int mf = 0; mf < 4; ++mf)
#pragma unroll
            for (int nf = 0; nf < 4; ++nf)
                acc[mf][nf] = __builtin_amdgcn_mfma_f32_16x16x32_bf16(
                    af[mf], bf0[nf], acc[mf][nf], 0, 0, 0);
#pragma unroll
        for (int mf = 0; mf < 4; ++mf)
#pragma unroll
            for (int nf = 0; nf < 4; ++nf)
                acc[mf][4 + nf] = __builtin_amdgcn_mfma_f32_16x16x32_bf16(
                    af[mf], bf1[nf], acc[mf][4 + nf], 0, 0, 0);
        __builtin_amdgcn_s_setprio(0);
    }

    // ---- per-wave epilogue, private 9KB slot (64 x 72 el) ----
    asm volatile("s_waitcnt lgkmcnt(0)" ::: "memory");
    __builtin_amdgcn_sched_barrier(0);
    bf16_t* slot = smem + wave * 4608;
    const int b = mBase >> 10, p0 = mBase & 1023;

#pragma unroll
    for (int half = 0; half < 2; ++half) {
        const int g64 = tx * 4 + wn * 2 + half;
        const int cls = g64 % 3, h = g64 / 3;
        if (cls == 0) {
#pragma unroll
            for (int mf = 0; mf < 4; ++mf)
#pragma unroll
                for (int nfl = 0; nfl < 4; ++nfl)
#pragma unroll
                    for (int i = 0; i < 4; ++i)
                        slot[(mf * 16 + quad * 4 + i) * 72 + nfl * 16 + m16] =
                            (bf16_t)acc[mf][half * 4 + nfl][i];
            asm volatile("s_waitcnt lgkmcnt(0)" ::: "memory");
            __builtin_amdgcn_sched_barrier(0);
#pragma unroll
            for (int j = 0; j < 8; ++j) {
                int r = j * 8 + (lane >> 3), cc = lane & 7;
                bf16x8 val = *(const bf16x8*)(slot + r * 72 + cc * 8);
                *(bf16x8*)(q + ((size_t)(b * 1024 + p0 + wm * 64 + r)) * 768 +
                           h * 64 + cc * 8) = val;
            }
        } else {
            bf16_t* dst = (cls == 1) ? kt : vt;
            const size_t bh = (size_t)(b * 12 + h);
#pragma unroll
            for (int mf = 0; mf < 4; ++mf)
#pragma unroll
                for (int nfl = 0; nfl < 4; ++nfl) {
                    int c = nfl * 16 + m16;
                    union { bf16_t hh[4]; uint2 u; } pk;
#pragma unroll
                    for (int i = 0; i < 4; ++i)
                        pk.hh[i] = (bf16_t)acc[mf][half * 4 + nfl][i];
                    *(uint2*)(slot + c * 72 + mf * 16 + quad * 4) = pk.u;
                }
            asm volatile("s_waitcnt lgkmcnt(0)" ::: "memory");
            __builtin_amdgcn_sched_barrier(0);
#pragma unroll
            for (int j = 0; j < 8; ++j) {
                int c = (lane >> 3) + j * 8, r8 = (lane & 7) * 8;
                bf16x8 val = *(const bf16x8*)(slot + c * 72 + r8);
                *(bf16x8*)(dst + (bh * 64 + c) * 1024 + p0 + wm * 64 + r8) = val;
            }
        }
        if (half == 0) {
            asm volatile("s_waitcnt lgkmcnt(0)" ::: "memory");
            __builtin_amdgcn_sched_barrier(0);
        }
    }
}

// ---------------------------------------------------------------------------
// kv_part: partial T tiles. grid (192, 2): block (bh, c) computes the 64x64
// fp32 partial of K^T V over P rows [c*512, c*512+512), 4 waves x 128 rows,
// LDS reduce, one fp32 tile out. 2x the read parallelism of the fused kvu
// (384 blocks streaming the 50MB kt/vt).
// ---------------------------------------------------------------------------
__global__ __launch_bounds__(256) void kv_part_kernel(const bf16_t* __restrict__ kt,
                                                      const bf16_t* __restrict__ vt,
                                                      float* __restrict__ partial) {
    __shared__ float red[4 * 64 * 65];   // 66.6 KB
    const int bh = blockIdx.x, c = blockIdx.y;
    const bf16_t* Kb = kt + (size_t)bh * DH * PP;
    const bf16_t* Vb = vt + (size_t)bh * DH * PP;
    const int t = threadIdx.x;
    const int lane = t & 63, wave = t >> 6;
    const int m16 = lane & 15, quad = lane >> 4;
    const f32x4 z = {0.f, 0.f, 0.f, 0.f};
    f32x4 acc[4][4];
#pragma unroll
    for (int mm = 0; mm < 4; ++mm)
#pragma unroll
        for (int nn = 0; nn < 4; ++nn) acc[mm][nn] = z;

#pragma unroll
    for (int ks = 0; ks < 4; ++ks) {
        int kb = c * 512 + wave * 128 + ks * 32 + quad * 8;
        bf16x8 af[4], bfv[4];
#pragma unroll
        for (int mm = 0; mm < 4; ++mm)
            af[mm] = *(const bf16x8*)(Kb + (size_t)(mm * 16 + m16) * PP + kb);
#pragma unroll
        for (int nn = 0; nn < 4; ++nn)
            bfv[nn] = *(const bf16x8*)(Vb + (size_t)(nn * 16 + m16) * PP + kb);
#pragma unroll
        for (int mm = 0; mm < 4; ++mm)
#pragma unroll
            for (int nn = 0; nn < 4; ++nn)
                acc[mm][nn] = __builtin_amdgcn_mfma_f32_16x16x32_bf16(
                    af[mm], bfv[nn], acc[mm][nn], 0, 0, 0);
    }
#pragma unroll
    for (int mm = 0; mm < 4; ++mm)
#pragma unroll
        for (int nn = 0; nn < 4; ++nn)
#pragma unroll
            for (int i = 0; i < 4; ++i)
                red[wave * 4160 + (mm * 16 + quad * 4 + i) * 65 + nn * 16 + m16] =
                    acc[mm][nn][i];
    __syncthreads();
    float* dst = partial + (size_t)(bh * 2 + c) * 4096;
#pragma unroll
    for (int j = 0; j < 4; ++j) {
        int f0 = j * 1024 + t * 4;       // [0,4096), 16B aligned
        int m = f0 >> 6, n = f0 & 63;
        int a = m * 65 + n;
        float4 s;
        s.x = red[a]     + red[4160 + a]     + red[8320 + a]     + red[12480 + a];
        s.y = red[a + 1] + red[4160 + a + 1] + red[8320 + a + 1] + red[12480 + a + 1];
        s.z = red[a + 2] + red[4160 + a + 2] + red[8320 + a + 2] + red[12480 + a + 2];
        s.w = red[a + 3] + red[4160 + a + 3] + red[8320 + a + 3] + red[12480 + a + 3];
        *(float4*)(dst + f0) = s;
    }
}

// ---------------------------------------------------------------------------
// u: sums the 2 fp32 partials per head inline -> T hi/lo frags -> U = T @
// lin_w slice, stored transposed as Ut[b][e][h*64+d1]. grid (192, 3), no LDS.
// ---------------------------------------------------------------------------
__global__ __launch_bounds__(256) void u_kernel(const float* __restrict__ partial,
                                                const bf16_t* __restrict__ lwT,
                                                bf16_t* __restrict__ ut) {
    const int bh = blockIdx.x;
    const int b = bh / NH, h = bh - b * NH;
    const int nBase = blockIdx.y * 256;
    const int t = threadIdx.x, lane = t & 63, wave = t >> 6;
    const int wm = wave >> 1, wn = wave & 1;
    const int m16 = lane & 15, quad = lane >> 4;
    const f32x4 z = {0.f, 0.f, 0.f, 0.f};
    const float* P0 = partial + (size_t)(bh * 2) * 4096;
    const float* P1 = P0 + 4096;

    bf16x8 ah[2][2], al[2][2];
#pragma unroll
    for (int mm = 0; mm < 2; ++mm)
#pragma unroll
        for (int ks = 0; ks < 2; ++ks) {
            int d1 = wm * 32 + mm * 16 + m16;
            int off = d1 * 64 + ks * 32 + quad * 8;
            float4 a0 = *(const float4*)(P0 + off),     a1 = *(const float4*)(P0 + off + 4);
            float4 b0 = *(const float4*)(P1 + off),     b1 = *(const float4*)(P1 + off + 4);
            float sv[8] = { a0.x + b0.x, a0.y + b0.y, a0.z + b0.z, a0.w + b0.w,
                            a1.x + b1.x, a1.y + b1.y, a1.z + b1.z, a1.w + b1.w };
#pragma unroll
            for (int e = 0; e < 8; ++e) {
                bf16_t hi = (bf16_t)sv[e];
                ah[mm][ks][e] = hi;
                al[mm][ks][e] = (bf16_t)(sv[e] - (float)hi);
            }
        }

#pragma unroll
    for (int ks = 0; ks < 2; ++ks) {
        bf16x8 bfr[8];
#pragma unroll
        for (int nn = 0; nn < 8; ++nn)
            bfr[nn] = *(const bf16x8*)(
                lwT + (size_t)(nBase + wn * 128 + nn * 16 + m16) * 768 +
                h * 64 + ks * 32 + quad * 8);
        static f32x4 dummy;  // (unused; keeps structure clear)
        (void)dummy;
        if (ks == 0) {
            // initialize accumulators on first ks pass
        }
        // accumulate below
        // (loop body continues after both ks frag loads in acc2 section)
        // -- handled in unified loop below --
        break;
    }

    f32x4 acc2[2][8];
#pragma unroll
    for (int mm = 0; mm < 2; ++mm)
#pragma unroll
        for (int nn = 0; nn < 8; ++nn) acc2[mm][nn] = z;
#pragma unroll
    for (int ks = 0; ks < 2; ++ks) {
        bf16x8 bfr[8];
#pragma unroll
        for (int nn = 0; nn < 8; ++nn)
            bfr[nn] = *(const bf16x8*)(
                lwT + (size_t)(nBase + wn * 128 + nn * 16 + m16) * 768 +
                h * 64 + ks * 32 + quad * 8);
#pragma unroll
        for (int mm = 0; mm < 2; ++mm)
#pragma unroll
            for (int nn = 0; nn < 8; ++nn) {
                acc2[mm][nn] = __builtin_amdgcn_mfma_f32_16x16x32_bf16(
                    ah[mm][ks], bfr[nn], acc2[mm][nn], 0, 0, 0);
                acc2[mm][nn] = __builtin_amdgcn_mfma_f32_16x16x32_bf16(
                    al[mm][ks], bfr[nn], acc2[mm][nn], 0, 0, 0);
            }
    }
#pragma unroll
    for (int mm = 0; mm < 2; ++mm)
#pragma unroll
        for (int nn = 0; nn < 8; ++nn) {
            int e  = nBase + wn * 128 + nn * 16 + m16;
            int d1 = wm * 32 + mm * 16 + quad * 4;
            union { bf16_t hh[4]; uint2 u; } pk;
#pragma unroll
            for (int i = 0; i < 4; ++i) pk.hh[i] = (bf16_t)acc2[mm][nn][i];
            *(uint2*)(ut + ((size_t)b * 768 + e) * 768 + h * 64 + d1) = pk.u;
        }
}

// ---------------------------------------------------------------------------
// Final GEMM: out = relu(q @ U^b + lin_b) + x (fp32 out). grid (6,128) = 768
// blocks = 3 exact rounds at 3 blk/CU. float4 epilogue via fp32 LDS.
// ---------------------------------------------------------------------------
__global__ __launch_bounds__(256, 3) void gemm_out_kernel(const bf16_t* __restrict__ q,
                                                          const bf16_t* __restrict__ ut,
                                                          const float* __restrict__ linb,
                                                          const float* __restrict__ x,
                                                          float* __restrict__ out) {
    __shared__ bf16_t smem[24576];   // 48KB K-loop; epilogue reuse as fp32
    const int lb  = blockIdx.y * 6 + blockIdx.x;
    const int swz = (lb & 7) * 96 + (lb >> 3);      // 768/8 = 96 per XCD
    const int tx  = swz % 6, ty = swz / 6;
    const int mBase = ty * 128, nBase = tx * 128;
    const int b = mBase >> 10;

    f32x4 acc[4][4];
    core128_bk32(q, ut + (size_t)b * 768 * 768, mBase, nBase, acc, smem);

    const int lane = threadIdx.x & 63, wave = threadIdx.x >> 6;
    const int wm = wave >> 1, wn = wave & 1;
    const int m16 = lane & 15, quad = lane >> 4;

    asm volatile("s_waitcnt lgkmcnt(0)" ::: "memory");
    __builtin_amdgcn_sched_barrier(0);
    __syncthreads();   // all waves done with K-loop LDS before fp32 reuse

    float* fslot = (float*)smem + wave * 2176;   // 32 x 68 fp32 per wave
    const int cl = lane & 15, rq = lane >> 4;
    const int colBase = nBase + wn * 64;
    const float4 lb4 = *(const float4*)(linb + colBase + cl * 4);

#pragma unroll
    for (int p = 0; p < 2; ++p) {
#pragma unroll
        for (int mm = 0; mm < 2; ++mm)
#pragma unroll
            for (int nn = 0; nn < 4; ++nn)
#pragma unroll
                for (int i = 0; i < 4; ++i)
                    fslot[(mm * 16 + quad * 4 + i) * 68 + nn * 16 + m16] =
                        acc[p * 2 + mm][nn][i];
        asm volatile("s_waitcnt lgkmcnt(0)" ::: "memory");
        __builtin_amdgcn_sched_barrier(0);
#pragma unroll
        for (int j = 0; j < 8; ++j) {
            int lr = j * 4 + rq;
            size_t row = (size_t)(mBase + wm * 64 + p * 32 + lr);
            float4 v4 = *(const float4*)(fslot + lr * 68 + cl * 4);
            float4 x4 = *(const float4*)(x + row * EE + colBase + cl * 4);
            float4 o4;
            o4.x = fmaxf(v4.x + lb4.x, 0.f) + x4.x;
            o4.y = fmaxf(v4.y + lb4.y, 0.f) + x4.y;
            o4.z = fmaxf(v4.z + lb4.z, 0.f) + x4.z;
            o4.w = fmaxf(v4.w + lb4.w, 0.f) + x4.w;
            *(float4*)(out + row * EE + colBase + cl * 4) = o4;
        }
        if (p == 0) {
            asm volatile("s_waitcnt lgkmcnt(0)" ::: "memory");
            __builtin_amdgcn_sched_barrier(0);
        }
    }
}

// ---------------------------------------------------------------------------
// Launch
// ---------------------------------------------------------------------------
extern "C" void kernel_launch(void* const* d_in, const int* in_sizes, int n_in,
                              void* d_out, int out_size, void* d_ws, size_t ws_size,
                              hipStream_t stream) {
    const float* x    = (const float*)d_in[0];
    const float* lnw  = (const float*)d_in[1];
    const float* lnb  = (const float*)d_in[2];
    const float* qkvw = (const float*)d_in[3];
    const float* linw = (const float*)d_in[4];
    const float* linb = (const float*)d_in[5];
    float* out = (float*)d_out;
    char* ws = (char*)d_ws;

    // Workspace layout (bytes), total ~105.4 MB. Rotations:
    //   xn dead after gemm_qkv -> ut (18.87 MB) + partial (6.29 MB) live there
    //   (18874368 + 6291456 = 25165824 = xn region exactly).
    float*  part    = (float*)(ws + 0);          //  8192 B
    bf16_t* xn      = (bf16_t*)(ws + 8448);      //  25165824 B
    bf16_t* qkvT    = (bf16_t*)(ws + 25174272);  //   3538944 B
    bf16_t* lwT     = (bf16_t*)(ws + 28713216);  //   1179648 B
    bf16_t* q       = (bf16_t*)(ws + 29892864);  //  25165824 B  (B,P,HID)
    bf16_t* kt      = (bf16_t*)(ws + 55058688);  //  25165824 B
    bf16_t* vt      = (bf16_t*)(ws + 80224512);  //  25165824 B -> end 105390336
    bf16_t* ut      = xn;                        //  18874368 B (xn dead after qkv)
    float*  partial = (float*)(ws + 8448 + 18874368);  // 6291456 B

    stats_prep_kernel<<<dim3(1600), dim3(256), 0, stream>>>(x, qkvw, linw, part,
                                                            qkvT, lwT);
    ln_apply_kernel<<<dim3(6144), dim3(256), 0, stream>>>(x, lnw, lnb, part, xn);
    gemm_qkv_kernel<<<dim3(9, 128), dim3(256), 0, stream>>>(xn, qkvT, q, kt, vt);
    kv_part_kernel<<<dim3(192, 2), dim3(256), 0, stream>>>(kt, vt, partial);
    u_kernel<<<dim3(192, 3), dim3(256), 0, stream>>>(partial, lwT, ut);
    gemm_out_kernel<<<dim3(6, 128), dim3(256), 0, stream>>>(q, ut, linb, x, out);
}

// Round 12
// 241.738 us; speedup vs baseline: 1.0501x; 1.0501x over previous
//
#include <hip/hip_runtime.h>
#include <hip/hip_bf16.h>
#include <cstdint>

// Problem constants
#define BB   16
#define PP   1024
#define EE   768
#define HID  768
#define NH   12
#define DH   64
#define NPB  (PP * EE)          // 786432 elements per batch
#define MROWS (BB * PP)         // 16384

typedef __bf16 bf16_t;
typedef __bf16 bf16x8 __attribute__((ext_vector_type(8)));
typedef float  f32x4  __attribute__((ext_vector_type(4)));

// Async global->LDS 16B DMA. LDS dest must be wave-uniform base + lane*16.
__device__ __forceinline__ void gld16(const void* g, void* l) {
    __builtin_amdgcn_global_load_lds(
        (const __attribute__((address_space(1))) void*)(uintptr_t)g,
        (__attribute__((address_space(3))) void*)(uint32_t)(uintptr_t)l,
        16, 0, 0);
}

// ---------------------------------------------------------------------------
// stats+prep fused: blocks [0,1024): per-slice partial sums of x.
// [1024,1456): qkvT transpose tiles; [1456,1600): lwT tiles.
// ---------------------------------------------------------------------------
__global__ __launch_bounds__(256) void stats_prep_kernel(const float* __restrict__ x,
                                                         const float* __restrict__ qkvw,
                                                         const float* __restrict__ linw,
                                                         float* __restrict__ part,
                                                         bf16_t* __restrict__ qkvT,
                                                         bf16_t* __restrict__ lwT) {
    int bid = blockIdx.x;
    if (bid < 1024) {
        int b = bid >> 6, s = bid & 63;
        const float4* xp = (const float4*)(x + (size_t)b * NPB + (size_t)s * 12288);
        float sum = 0.f, ss = 0.f;
#pragma unroll
        for (int i = 0; i < 12; ++i) {
            float4 v = xp[i * 256 + threadIdx.x];
            sum += v.x + v.y + v.z + v.w;
            ss  += v.x * v.x + v.y * v.y + v.z * v.z + v.w * v.w;
        }
#pragma unroll
        for (int off = 32; off > 0; off >>= 1) {
            sum += __shfl_down(sum, off, 64);
            ss  += __shfl_down(ss,  off, 64);
        }
        __shared__ float tmp[8];
        int wave = threadIdx.x >> 6, lane = threadIdx.x & 63;
        if (lane == 0) { tmp[wave * 2] = sum; tmp[wave * 2 + 1] = ss; }
        __syncthreads();
        if (threadIdx.x == 0) {
            part[bid * 2]     = tmp[0] + tmp[2] + tmp[4] + tmp[6];
            part[bid * 2 + 1] = tmp[1] + tmp[3] + tmp[5] + tmp[7];
        }
    } else {
        __shared__ float lds[64][65];
        int pid = bid - 1024;
        const float* src; bf16_t* dst; int r0, c0, W;
        if (pid < 432) {
            int tr = pid / 36, tc = pid - tr * 36;
            r0 = tr * 64; c0 = tc * 64; src = qkvw; W = 2304; dst = qkvT;
        } else {
            int bb = pid - 432;
            int tr = bb / 12, tc = bb - tr * 12;
            r0 = tr * 64; c0 = tc * 64; src = linw; W = 768; dst = lwT;
        }
        int t = threadIdx.x;
        int rr = t >> 4, cc4 = (t & 15) * 4;
#pragma unroll
        for (int j = 0; j < 4; ++j) {
            float4 v = *(const float4*)(src + (size_t)(r0 + rr + j * 16) * W + c0 + cc4);
            lds[rr + j * 16][cc4 + 0] = v.x;
            lds[rr + j * 16][cc4 + 1] = v.y;
            lds[rr + j * 16][cc4 + 2] = v.z;
            lds[rr + j * 16][cc4 + 3] = v.w;
        }
        __syncthreads();
        int cl = t >> 3, rgl = (t & 7) * 8;
#pragma unroll
        for (int jj = 0; jj < 2; ++jj) {
            int c = jj * 32 + cl;
            union { bf16_t h[8]; uint4 u; } o;
#pragma unroll
            for (int k = 0; k < 8; ++k) o.h[k] = (bf16_t)lds[rgl + k][c];
            *(uint4*)(dst + (size_t)(c0 + c) * 768 + r0 + rgl) = o.u;
        }
    }
}

// ---------------------------------------------------------------------------
// ln_apply: fp32 x read + inline stats finalize (64 partial pairs per batch,
// L2-hot). b uniform per block.
// ---------------------------------------------------------------------------
__global__ __launch_bounds__(256) void ln_apply_kernel(const float* __restrict__ x,
                                                       const float* __restrict__ lnw,
                                                       const float* __restrict__ lnb,
                                                       const float* __restrict__ part,
                                                       bf16_t* __restrict__ xn) {
    int i = (blockIdx.x * 256 + threadIdx.x) * 8;
    int b = i / NPB;
    int r = i - b * NPB;
    int lane = threadIdx.x & 63;
    float sum = part[(b * 64 + lane) * 2];
    float ss  = part[(b * 64 + lane) * 2 + 1];
#pragma unroll
    for (int off = 32; off > 0; off >>= 1) {
        sum += __shfl_down(sum, off, 64);
        ss  += __shfl_down(ss,  off, 64);
    }
    const float inv_n = 1.f / (float)NPB;
    float mean = __shfl(sum, 0, 64) * inv_n;
    float var  = __shfl(ss,  0, 64) * inv_n - mean * mean;
    float rstd = rsqrtf(var + 1e-5f);

    float4 x0 = *(const float4*)(x + i),     x1 = *(const float4*)(x + i + 4);
    float4 w0 = *(const float4*)(lnw + r),   w1 = *(const float4*)(lnw + r + 4);
    float4 c0 = *(const float4*)(lnb + r),   c1 = *(const float4*)(lnb + r + 4);
    union { bf16_t h[8]; uint4 u; } o;
    o.h[0] = (bf16_t)((x0.x - mean) * rstd * w0.x + c0.x);
    o.h[1] = (bf16_t)((x0.y - mean) * rstd * w0.y + c0.y);
    o.h[2] = (bf16_t)((x0.z - mean) * rstd * w0.z + c0.z);
    o.h[3] = (bf16_t)((x0.w - mean) * rstd * w0.w + c0.w);
    o.h[4] = (bf16_t)((x1.x - mean) * rstd * w1.x + c1.x);
    o.h[5] = (bf16_t)((x1.y - mean) * rstd * w1.y + c1.y);
    o.h[6] = (bf16_t)((x1.z - mean) * rstd * w1.z + c1.z);
    o.h[7] = (bf16_t)((x1.w - mean) * rstd * w1.w + c1.w);
    *(uint4*)(xn + i) = o.u;
}

// ---------------------------------------------------------------------------
// Shared core (gemm_out): 128x128 tile, BK=32, TRIPLE-buffered (48KB ->
// 3 blocks/CU), counted vmcnt(8), 4 waves (2Mx2N, wave tile 64x64).
// ---------------------------------------------------------------------------
__device__ __forceinline__ void core128_bk32(const bf16_t* __restrict__ A,
                                             const bf16_t* __restrict__ Bt,
                                             int mBase, int nBase,
                                             f32x4 acc[4][4], bf16_t* smem) {
    const int t = threadIdx.x, lane = t & 63, wave = t >> 6;
    const int wm = wave >> 1, wn = wave & 1;
    const int m16 = lane & 15, quad = lane >> 4;

    const bf16_t* gsrc[4];
    int ldst[4];
#pragma unroll
    for (int j = 0; j < 2; ++j) {
        int c = t + 256 * j;
        int l = c >> 3, lg = ((c & 7) - (l & 7)) & 7;
        int row = l + (lg >> 2) * 64, kc = lg & 3;
        gsrc[j]     = A  + (size_t)(mBase + row) * 768 + kc * 8;
        ldst[j]     = c * 8;
        gsrc[2 + j] = Bt + (size_t)(nBase + row) * 768 + kc * 8;
        ldst[2 + j] = 4096 + c * 8;
    }

    int aOff[4], bOff[4];
#pragma unroll
    for (int f = 0; f < 4; ++f) {
        aOff[f] = (f * 16 + m16) * 64 + (((wm * 4 + quad) + (m16 & 7)) & 7) * 8;
        bOff[f] = 4096 + (f * 16 + m16) * 64 + (((wn * 4 + quad) + (m16 & 7)) & 7) * 8;
    }

    const f32x4 z = {0.f, 0.f, 0.f, 0.f};
#pragma unroll
    for (int mf = 0; mf < 4; ++mf)
#pragma unroll
        for (int nf = 0; nf < 4; ++nf) acc[mf][nf] = z;

#pragma unroll
    for (int j = 0; j < 4; ++j) gld16(gsrc[j], smem + ldst[j]);
#pragma unroll
    for (int j = 0; j < 4; ++j) gld16(gsrc[j] + 32, smem + 8192 + ldst[j]);

#pragma unroll
    for (int step = 0; step < 24; ++step) {
        const int cur = (step % 3) * 8192;
        asm volatile("s_waitcnt lgkmcnt(0)" ::: "memory");
        __builtin_amdgcn_sched_barrier(0);
        __builtin_amdgcn_s_barrier();
        if (step + 2 < 24) {
            const int nb = ((step + 2) % 3) * 8192;
            const int kq = (step + 2) * 32;
#pragma unroll
            for (int j = 0; j < 4; ++j)
                gld16(gsrc[j] + kq, smem + nb + ldst[j]);
        }
        if (step < 22)       asm volatile("s_waitcnt vmcnt(8)" ::: "memory");
        else if (step == 22) asm volatile("s_waitcnt vmcnt(4)" ::: "memory");
        else                 asm volatile("s_waitcnt vmcnt(0)" ::: "memory");
        __builtin_amdgcn_sched_barrier(0);
        __builtin_amdgcn_s_barrier();

        bf16x8 af[4], bfv[4];
#pragma unroll
        for (int f = 0; f < 4; ++f) {
            af[f]  = *(const bf16x8*)(smem + cur + aOff[f]);
            bfv[f] = *(const bf16x8*)(smem + cur + bOff[f]);
        }
        __builtin_amdgcn_s_setprio(1);
#pragma unroll
        for (int mf = 0; mf < 4; ++mf)
#pragma unroll
            for (int nf = 0; nf < 4; ++nf)
                acc[mf][nf] = __builtin_amdgcn_mfma_f32_16x16x32_bf16(
                    af[mf], bfv[nf], acc[mf][nf], 0, 0, 0);
        __builtin_amdgcn_s_setprio(0);
    }
}

// ---------------------------------------------------------------------------
// GEMM1 (frozen): tile 128x256, 4 waves, BK=32, triple-buffered (72KB,
// 2 blk/CU), counted vmcnt(12), no mid-step barrier, odd-block anti-phase
// stagger. grid (9,128), 256 thr.
// ---------------------------------------------------------------------------
__global__ __launch_bounds__(256, 2) void gemm_qkv_kernel(const bf16_t* __restrict__ xn,
                                                          const bf16_t* __restrict__ qkvT,
                                                          bf16_t* __restrict__ q,
                                                          bf16_t* __restrict__ kt,
                                                          bf16_t* __restrict__ vt) {
    __shared__ bf16_t smem[36864];   // 72KB: 3 x (A 8KB | B 16KB)
    const int t = threadIdx.x, lane = t & 63, wave = t >> 6;
    const int wm = wave >> 1, wn = wave & 1;
    const int m16 = lane & 15, quad = lane >> 4;

    const int lb = blockIdx.y * 9 + blockIdx.x;
    if (lb & 1) __builtin_amdgcn_s_sleep(28);   // ~1800 cy anti-phase stagger
    const int id = (lb & 7) * 144 + (lb >> 3);
    const int tx = id % 9, ty = id / 9;
    const int mBase = ty * 128, nBase = tx * 256;

    const bf16_t* gsrc[6];
    int ldst[6];
#pragma unroll
    for (int j = 0; j < 2; ++j) {
        int c = t + 256 * j;
        int l = c >> 3, lg = ((c & 7) - (l & 7)) & 7;
        gsrc[j] = xn + (size_t)(mBase + l + (lg >> 2) * 64) * 768 + (lg & 3) * 8;
        ldst[j] = c * 8;
    }
#pragma unroll
    for (int j = 0; j < 4; ++j) {
        int c = t + 256 * j;
        int l = c >> 3, lg = ((c & 7) - (l & 7)) & 7;
        gsrc[2 + j] = qkvT + (size_t)(nBase + l + (lg >> 2) * 128) * 768 + (lg & 3) * 8;
        ldst[2 + j] = 4096 + c * 8;
    }

    int aOff[4], bOff[8];
#pragma unroll
    for (int mf = 0; mf < 4; ++mf)
        aOff[mf] = (mf * 16 + m16) * 64 + (((wm * 4 + quad) + (m16 & 7)) & 7) * 8;
#pragma unroll
    for (int nf = 0; nf < 8; ++nf)
        bOff[nf] = 4096 + (nf * 16 + m16) * 64 + (((wn * 4 + quad) + (m16 & 7)) & 7) * 8;

    f32x4 acc[4][8];
    const f32x4 z = {0.f, 0.f, 0.f, 0.f};
#pragma unroll
    for (int mf = 0; mf < 4; ++mf)
#pragma unroll
        for (int nf = 0; nf < 8; ++nf) acc[mf][nf] = z;

#pragma unroll
    for (int j = 0; j < 6; ++j) gld16(gsrc[j], smem + ldst[j]);
#pragma unroll
    for (int j = 0; j < 6; ++j) gld16(gsrc[j] + 32, smem + 12288 + ldst[j]);

#pragma unroll
    for (int step = 0; step < 24; ++step) {
        const int cur = (step % 3) * 12288;
        asm volatile("s_waitcnt lgkmcnt(0)" ::: "memory");
        __builtin_amdgcn_sched_barrier(0);
        __builtin_amdgcn_s_barrier();
        if (step + 2 < 24) {
            const int nb = ((step + 2) % 3) * 12288;
            const int kq = (step + 2) * 32;
#pragma unroll
            for (int j = 0; j < 6; ++j)
                gld16(gsrc[j] + kq, smem + nb + ldst[j]);
        }
        if (step < 22)       asm volatile("s_waitcnt vmcnt(12)" ::: "memory");
        else if (step == 22) asm volatile("s_waitcnt vmcnt(6)"  ::: "memory");
        else                 asm volatile("s_waitcnt vmcnt(0)"  ::: "memory");
        __builtin_amdgcn_sched_barrier(0);
        __builtin_amdgcn_s_barrier();    // buf[step] globally ready

        bf16x8 af[4], bf0[4], bf1[4];
#pragma unroll
        for (int mf = 0; mf < 4; ++mf)
            af[mf] = *(const bf16x8*)(smem + cur + aOff[mf]);
#pragma unroll
        for (int nf = 0; nf < 4; ++nf)
            bf0[nf] = *(const bf16x8*)(smem + cur + bOff[nf]);
#pragma unroll
        for (int nf = 0; nf < 4; ++nf)
            bf1[nf] = *(const bf16x8*)(smem + cur + bOff[4 + nf]);
        __builtin_amdgcn_s_setprio(1);
#pragma unroll
        for (int mf = 0; mf < 4; ++mf)
#pragma unroll
            for (int nf = 0; nf < 4; ++nf)
                acc[mf][nf] = __builtin_amdgcn_mfma_f32_16x16x32_bf16(
                    af[mf], bf0[nf], acc[mf][nf], 0, 0, 0);
#pragma unroll
        for (int mf = 0; mf < 4; ++mf)
#pragma unroll
            for (int nf = 0; nf < 4; ++nf)
                acc[mf][4 + nf] = __builtin_amdgcn_mfma_f32_16x16x32_bf16(
                    af[mf], bf1[nf], acc[mf][4 + nf], 0, 0, 0);
        __builtin_amdgcn_s_setprio(0);
    }

    // ---- per-wave epilogue, private 9KB slot (64 x 72 el) ----
    asm volatile("s_waitcnt lgkmcnt(0)" ::: "memory");
    __builtin_amdgcn_sched_barrier(0);
    bf16_t* slot = smem + wave * 4608;
    const int b = mBase >> 10, p0 = mBase & 1023;

#pragma unroll
    for (int half = 0; half < 2; ++half) {
        const int g64 = tx * 4 + wn * 2 + half;
        const int cls = g64 % 3, h = g64 / 3;
        if (cls == 0) {
#pragma unroll
            for (int mf = 0; mf < 4; ++mf)
#pragma unroll
                for (int nfl = 0; nfl < 4; ++nfl)
#pragma unroll
                    for (int i = 0; i < 4; ++i)
                        slot[(mf * 16 + quad * 4 + i) * 72 + nfl * 16 + m16] =
                            (bf16_t)acc[mf][half * 4 + nfl][i];
            asm volatile("s_waitcnt lgkmcnt(0)" ::: "memory");
            __builtin_amdgcn_sched_barrier(0);
#pragma unroll
            for (int j = 0; j < 8; ++j) {
                int r = j * 8 + (lane >> 3), cc = lane & 7;
                bf16x8 val = *(const bf16x8*)(slot + r * 72 + cc * 8);
                *(bf16x8*)(q + ((size_t)(b * 1024 + p0 + wm * 64 + r)) * 768 +
                           h * 64 + cc * 8) = val;
            }
        } else {
            bf16_t* dst = (cls == 1) ? kt : vt;
            const size_t bh = (size_t)(b * 12 + h);
#pragma unroll
            for (int mf = 0; mf < 4; ++mf)
#pragma unroll
                for (int nfl = 0; nfl < 4; ++nfl) {
                    int c = nfl * 16 + m16;
                    union { bf16_t hh[4]; uint2 u; } pk;
#pragma unroll
                    for (int i = 0; i < 4; ++i)
                        pk.hh[i] = (bf16_t)acc[mf][half * 4 + nfl][i];
                    *(uint2*)(slot + c * 72 + mf * 16 + quad * 4) = pk.u;
                }
            asm volatile("s_waitcnt lgkmcnt(0)" ::: "memory");
            __builtin_amdgcn_sched_barrier(0);
#pragma unroll
            for (int j = 0; j < 8; ++j) {
                int c = (lane >> 3) + j * 8, r8 = (lane & 7) * 8;
                bf16x8 val = *(const bf16x8*)(slot + c * 72 + r8);
                *(bf16x8*)(dst + (bh * 64 + c) * 1024 + p0 + wm * 64 + r8) = val;
            }
        }
        if (half == 0) {
            asm volatile("s_waitcnt lgkmcnt(0)" ::: "memory");
            __builtin_amdgcn_sched_barrier(0);
        }
    }
}

// ---------------------------------------------------------------------------
// kvu (fused, R9-best): T = K^T V per head (split-K over 4 waves, fp32 LDS
// reduce) then U = T @ lin_w slice via hi/lo bf16, stored transposed as
// Ut[b][e][h*64+d1]. T never leaves the block. grid (192).
// ---------------------------------------------------------------------------
__global__ __launch_bounds__(256) void kvu_kernel(const bf16_t* __restrict__ kt,
                                                  const bf16_t* __restrict__ vt,
                                                  const bf16_t* __restrict__ lwT,
                                                  bf16_t* __restrict__ ut) {
    __shared__ float red[4 * 64 * 65];   // 66.6 KB
    const int bh = blockIdx.x;
    const int b = bh / NH, h = bh - b * NH;
    const bf16_t* Kb = kt + (size_t)bh * DH * PP;
    const bf16_t* Vb = vt + (size_t)bh * DH * PP;
    const int t = threadIdx.x;
    const int lane = t & 63, wave = t >> 6;
    const int m16 = lane & 15, quad = lane >> 4;
    const f32x4 z = {0.f, 0.f, 0.f, 0.f};

    {
        f32x4 acc[4][4];
#pragma unroll
        for (int mm = 0; mm < 4; ++mm)
#pragma unroll
            for (int nn = 0; nn < 4; ++nn) acc[mm][nn] = z;
        for (int ks = 0; ks < 8; ++ks) {
            int kb = wave * 256 + ks * 32 + quad * 8;
            bf16x8 af[4], bfv[4];
#pragma unroll
            for (int mm = 0; mm < 4; ++mm)
                af[mm] = *(const bf16x8*)(Kb + (size_t)(mm * 16 + m16) * PP + kb);
#pragma unroll
            for (int nn = 0; nn < 4; ++nn)
                bfv[nn] = *(const bf16x8*)(Vb + (size_t)(nn * 16 + m16) * PP + kb);
#pragma unroll
            for (int mm = 0; mm < 4; ++mm)
#pragma unroll
                for (int nn = 0; nn < 4; ++nn)
                    acc[mm][nn] = __builtin_amdgcn_mfma_f32_16x16x32_bf16(
                        af[mm], bfv[nn], acc[mm][nn], 0, 0, 0);
        }
#pragma unroll
        for (int mm = 0; mm < 4; ++mm)
#pragma unroll
            for (int nn = 0; nn < 4; ++nn)
#pragma unroll
                for (int i = 0; i < 4; ++i)
                    red[wave * 4160 + (mm * 16 + quad * 4 + i) * 65 + nn * 16 + m16] =
                        acc[mm][nn][i];
    }
    __syncthreads();

    const int wm = wave >> 1, wn = wave & 1;
    bf16x8 ah[2][2], al[2][2];
#pragma unroll
    for (int mm = 0; mm < 2; ++mm)
#pragma unroll
        for (int ks = 0; ks < 2; ++ks) {
            int d1 = wm * 32 + mm * 16 + m16;
            int base = d1 * 65 + ks * 32 + quad * 8;
#pragma unroll
            for (int e = 0; e < 8; ++e) {
                float s = red[base + e] + red[4160 + base + e] +
                          red[8320 + base + e] + red[12480 + base + e];
                bf16_t hi = (bf16_t)s;
                ah[mm][ks][e] = hi;
                al[mm][ks][e] = (bf16_t)(s - (float)hi);
            }
        }

#pragma unroll
    for (int ny = 0; ny < 3; ++ny) {
        const int nBase = ny * 256;
        f32x4 acc2[2][8];
#pragma unroll
        for (int mm = 0; mm < 2; ++mm)
#pragma unroll
            for (int nn = 0; nn < 8; ++nn) acc2[mm][nn] = z;
#pragma unroll
        for (int ks = 0; ks < 2; ++ks) {
            bf16x8 bfr[8];
#pragma unroll
            for (int nn = 0; nn < 8; ++nn)
                bfr[nn] = *(const bf16x8*)(
                    lwT + (size_t)(nBase + wn * 128 + nn * 16 + m16) * 768 +
                    h * 64 + ks * 32 + quad * 8);
#pragma unroll
            for (int mm = 0; mm < 2; ++mm)
#pragma unroll
                for (int nn = 0; nn < 8; ++nn) {
                    acc2[mm][nn] = __builtin_amdgcn_mfma_f32_16x16x32_bf16(
                        ah[mm][ks], bfr[nn], acc2[mm][nn], 0, 0, 0);
                    acc2[mm][nn] = __builtin_amdgcn_mfma_f32_16x16x32_bf16(
                        al[mm][ks], bfr[nn], acc2[mm][nn], 0, 0, 0);
                }
        }
#pragma unroll
        for (int mm = 0; mm < 2; ++mm)
#pragma unroll
            for (int nn = 0; nn < 8; ++nn) {
                int e  = nBase + wn * 128 + nn * 16 + m16;
                int d1 = wm * 32 + mm * 16 + quad * 4;
                union { bf16_t hh[4]; uint2 u; } pk;
#pragma unroll
                for (int i = 0; i < 4; ++i) pk.hh[i] = (bf16_t)acc2[mm][nn][i];
                *(uint2*)(ut + ((size_t)b * 768 + e) * 768 + h * 64 + d1) = pk.u;
            }
    }
}

// ---------------------------------------------------------------------------
// Final GEMM: out = relu(q @ U^b + lin_b) + x (fp32 out). grid (6,128) = 768
// blocks = 3 exact rounds at 3 blk/CU. float4 epilogue via fp32 LDS.
// ---------------------------------------------------------------------------
__global__ __launch_bounds__(256, 3) void gemm_out_kernel(const bf16_t* __restrict__ q,
                                                          const bf16_t* __restrict__ ut,
                                                          const float* __restrict__ linb,
                                                          const float* __restrict__ x,
                                                          float* __restrict__ out) {
    __shared__ bf16_t smem[24576];   // 48KB K-loop; epilogue reuse as fp32
    const int lb  = blockIdx.y * 6 + blockIdx.x;
    const int swz = (lb & 7) * 96 + (lb >> 3);      // 768/8 = 96 per XCD
    const int tx  = swz % 6, ty = swz / 6;
    const int mBase = ty * 128, nBase = tx * 128;
    const int b = mBase >> 10;

    f32x4 acc[4][4];
    core128_bk32(q, ut + (size_t)b * 768 * 768, mBase, nBase, acc, smem);

    const int lane = threadIdx.x & 63, wave = threadIdx.x >> 6;
    const int wm = wave >> 1, wn = wave & 1;
    const int m16 = lane & 15, quad = lane >> 4;

    asm volatile("s_waitcnt lgkmcnt(0)" ::: "memory");
    __builtin_amdgcn_sched_barrier(0);
    __syncthreads();   // all waves done with K-loop LDS before fp32 reuse

    float* fslot = (float*)smem + wave * 2176;   // 32 x 68 fp32 per wave
    const int cl = lane & 15, rq = lane >> 4;
    const int colBase = nBase + wn * 64;
    const float4 lb4 = *(const float4*)(linb + colBase + cl * 4);

#pragma unroll
    for (int p = 0; p < 2; ++p) {
#pragma unroll
        for (int mm = 0; mm < 2; ++mm)
#pragma unroll
            for (int nn = 0; nn < 4; ++nn)
#pragma unroll
                for (int i = 0; i < 4; ++i)
                    fslot[(mm * 16 + quad * 4 + i) * 68 + nn * 16 + m16] =
                        acc[p * 2 + mm][nn][i];
        asm volatile("s_waitcnt lgkmcnt(0)" ::: "memory");
        __builtin_amdgcn_sched_barrier(0);
#pragma unroll
        for (int j = 0; j < 8; ++j) {
            int lr = j * 4 + rq;
            size_t row = (size_t)(mBase + wm * 64 + p * 32 + lr);
            float4 v4 = *(const float4*)(fslot + lr * 68 + cl * 4);
            float4 x4 = *(const float4*)(x + row * EE + colBase + cl * 4);
            float4 o4;
            o4.x = fmaxf(v4.x + lb4.x, 0.f) + x4.x;
            o4.y = fmaxf(v4.y + lb4.y, 0.f) + x4.y;
            o4.z = fmaxf(v4.z + lb4.z, 0.f) + x4.z;
            o4.w = fmaxf(v4.w + lb4.w, 0.f) + x4.w;
            *(float4*)(out + row * EE + colBase + cl * 4) = o4;
        }
        if (p == 0) {
            asm volatile("s_waitcnt lgkmcnt(0)" ::: "memory");
            __builtin_amdgcn_sched_barrier(0);
        }
    }
}

// ---------------------------------------------------------------------------
// Launch
// ---------------------------------------------------------------------------
extern "C" void kernel_launch(void* const* d_in, const int* in_sizes, int n_in,
                              void* d_out, int out_size, void* d_ws, size_t ws_size,
                              hipStream_t stream) {
    const float* x    = (const float*)d_in[0];
    const float* lnw  = (const float*)d_in[1];
    const float* lnb  = (const float*)d_in[2];
    const float* qkvw = (const float*)d_in[3];
    const float* linw = (const float*)d_in[4];
    const float* linb = (const float*)d_in[5];
    float* out = (float*)d_out;
    char* ws = (char*)d_ws;

    // Workspace layout (bytes), total ~105.4 MB. Rotation:
    //   xn dead after gemm_qkv -> ut lives there (ut must NOT alias kt/vt,
    //   which kvu reads while writing ut).
    float*  part  = (float*)(ws + 0);          //  8192 B
    bf16_t* xn    = (bf16_t*)(ws + 8448);      //  25165824 B
    bf16_t* qkvT  = (bf16_t*)(ws + 25174272);  //   3538944 B
    bf16_t* lwT   = (bf16_t*)(ws + 28713216);  //   1179648 B
    bf16_t* q     = (bf16_t*)(ws + 29892864);  //  25165824 B  (B,P,HID)
    bf16_t* kt    = (bf16_t*)(ws + 55058688);  //  25165824 B
    bf16_t* vt    = (bf16_t*)(ws + 80224512);  //  25165824 B -> end 105390336
    bf16_t* ut    = xn;                        //  18874368 B (xn dead after qkv)

    stats_prep_kernel<<<dim3(1600), dim3(256), 0, stream>>>(x, qkvw, linw, part,
                                                            qkvT, lwT);
    ln_apply_kernel<<<dim3(6144), dim3(256), 0, stream>>>(x, lnw, lnb, part, xn);
    gemm_qkv_kernel<<<dim3(9, 128), dim3(256), 0, stream>>>(xn, qkvT, q, kt, vt);
    kvu_kernel<<<dim3(192), dim3(256), 0, stream>>>(kt, vt, lwT, ut);
    gemm_out_kernel<<<dim3(6, 128), dim3(256), 0, stream>>>(q, ut, linb, x, out);
}